// Round 6
// baseline (203.871 us; speedup 1.0000x reference)
//
#include <hip/hip_runtime.h>
#include <hip/hip_bf16.h>
#include <math.h>

// Problem constants
#define BROWS 16384
#define IN_DIM 128
#define HID 512
#define ATT 256
#define KTOT 896          // IN_DIM + HID + ATT
#define KC_TOT 112        // KTOT / 8

typedef __bf16 bf16x8 __attribute__((ext_vector_type(8)));
typedef float f32x4 __attribute__((ext_vector_type(4)));

// ---------------------------------------------------------------------------
// Kernel 1: pack augmented weights -> B_stage[jt(16)][kc(112)][nl(96)][8] bf16.
// nl = jg*48 + type*16 + j16 ; jg in [0,2), type 0=gate 1=dyn 2=tau.
// j = jt*32 + jg*16 + j16. tau rows nonzero only for k in [128,640).
// ---------------------------------------------------------------------------
__device__ __forceinline__ float softplus_f(float x) {
    return fmaxf(x, 0.0f) + log1pf(__expf(-fabsf(x)));
}

__global__ void pack_B(const float* __restrict__ W_gd, const float* __restrict__ W_tau,
                       const float* __restrict__ gleak, const float* __restrict__ cm,
                       __hip_bfloat16* __restrict__ B_stage, float* __restrict__ dconst) {
    const int cid = blockIdx.x * 256 + threadIdx.x;   // 672*256 = 172032 = 16*112*96
    if (cid < HID) {
        dconst[cid] = softplus_f(cm[cid]) + softplus_f(gleak[cid]) + 1e-6f;
    }
    const int nl = cid % 96;
    const int kc = (cid / 96) % KC_TOT;
    const int jt = cid / (96 * KC_TOT);
    const int jg = nl / 48, type = (nl % 48) / 16, j16 = nl % 16;
    const int j = jt * 32 + jg * 16 + j16;
    const int k0 = kc * 8;

    float v[8];
    if (type == 0) {
        const float* s = W_gd + (size_t)j * KTOT + k0;
        #pragma unroll
        for (int i = 0; i < 8; ++i) v[i] = s[i];
    } else if (type == 1) {
        const float* s = W_gd + (size_t)(HID + j) * KTOT + k0;
        #pragma unroll
        for (int i = 0; i < 8; ++i) v[i] = s[i];
    } else {
        if (k0 >= IN_DIM && k0 < IN_DIM + HID) {
            const float* s = W_tau + (size_t)j * HID + (k0 - IN_DIM);
            #pragma unroll
            for (int i = 0; i < 8; ++i) v[i] = s[i];
        } else {
            #pragma unroll
            for (int i = 0; i < 8; ++i) v[i] = 0.0f;
        }
    }
    union { __hip_bfloat16 hh[8]; uint4 u; } p;
    #pragma unroll
    for (int i = 0; i < 8; ++i) p.hh[i] = __float2bfloat16(v[i]);
    *(uint4*)(B_stage + (size_t)cid * 8) = p.u;
}

// ---------------------------------------------------------------------------
// Kernel 2: fused convert+GEMM+epilogue, DOUBLE-BUFFERED K-loop.
// One barrier per step; loads for slab ks+1 are issued BEFORE the compute
// phase of slab ks and drained by the barrier AFTER it (issue-early/drain-
// late: the vmcnt(0) the compiler emits at the barrier finds loads that have
// had a full compute phase in flight — the R5 structure drained them with
// ~zero in-flight time, exposing full latency at 28 barriers/block).
// A pipeline is 3-stage: global->pf regs (step ks-1), ds_write As[nxt]
// (step ks), consumed from LDS (step ks+1). B: global_load_lds -> Bs[nxt].
// Block: 512 threads (8 waves), tile 128(M) x 32(j) x {gate,dyn,tau}, BK=64.
// Waves: wm = wave>>1 (32-row quarter), wj = wave&1 (16-j group).
// Grid: 2048 blocks (mt = bx & 127 -> co-XCD A-tile siblings). 
// LDS: 2*(As 16KB) + 2*(Bs 12KB) = 56KB static -> 2 blocks/CU.
// Regs: acc 24 + pf 32 + misc -> well under the (512,4) cap of 128 (R3
// lesson: never let launch_bounds force a spill).
// ---------------------------------------------------------------------------
__device__ __forceinline__ void slab_src(int ks, const float* x, const float* h,
                                         const float* c, const float*& src,
                                         int& rs, int& c0) {
    if (ks < 2)       { src = x; rs = IN_DIM; c0 = ks * 64; }
    else if (ks < 10) { src = h; rs = HID;    c0 = (ks - 2) * 64; }
    else              { src = c; rs = ATT;    c0 = (ks - 10) * 64; }
}

__global__ __launch_bounds__(512, 4) void ltc_gemm(
    const float* __restrict__ x, const float* __restrict__ h_ltc,
    const float* __restrict__ ctx, const __hip_bfloat16* __restrict__ B_stage,
    const float* __restrict__ b_gd, const float* __restrict__ b_tau,
    const float* __restrict__ dconst, float* __restrict__ out) {

    __shared__ __attribute__((aligned(16))) char smem[2 * 16384 + 2 * 12288];

    const int bx = blockIdx.x;
    const int mt = bx & 127;    // A-tile id; bx % 8 == mt % 8 -> co-XCD siblings
    const int jt = bx >> 7;     // 0..15
    const int tid = threadIdx.x;
    const int wave = tid >> 6, lane = tid & 63;
    const int wm = wave >> 1;   // 0..3  (32-row quarter)
    const int wj = wave & 1;    // 0..1  (16-j group)
    const int q = lane >> 4, t = lane & 15;

    // A staging role: thread stages chunks (kc8, mi0) and (kc8, mi0+64)
    const int kc8 = tid & 7;    // k-chunk in slab
    const int mi0 = tid >> 3;   // 0..63

    f32x4 accg[2], accd[2], acct[2];
    #pragma unroll
    for (int i = 0; i < 2; ++i) {
        accg[i] = (f32x4)0.0f; accd[i] = (f32x4)0.0f; acct[i] = (f32x4)0.0f;
    }

    // B staging: 12 chunks of 1KB per slab; wave w stages c=w and (w<4) c=w+8.
    const __hip_bfloat16* bSrc0 = B_stage + (size_t)jt * (KC_TOT * 768)
                                + wave * 512 + lane * 8;
    const __hip_bfloat16* bSrc1 = bSrc0 + 8 * 512;  // chunk wave+8 (waves 0-3)

    // --- Prologue: slab 0 into buffers 0; prefetch slab 1 into pf[1] ---
    float4 pf[2][2][2];   // [slot][r][half]
    {
        const float* src; int rs, c0;
        slab_src(0, x, h_ltc, ctx, src, rs, c0);
        #pragma unroll
        for (int r = 0; r < 2; ++r) {
            const float* p = src + (size_t)(mt * 128 + mi0 + 64 * r) * rs + c0 + kc8 * 8;
            pf[0][r][0] = *(const float4*)p;
            pf[0][r][1] = *(const float4*)(p + 4);
        }
    }
    {
        char* As0 = smem;   // buffer 0
        #pragma unroll
        for (int r = 0; r < 2; ++r) {
            union { __hip_bfloat16 hh[8]; uint4 u; } pk;
            pk.hh[0] = __float2bfloat16(pf[0][r][0].x);
            pk.hh[1] = __float2bfloat16(pf[0][r][0].y);
            pk.hh[2] = __float2bfloat16(pf[0][r][0].z);
            pk.hh[3] = __float2bfloat16(pf[0][r][0].w);
            pk.hh[4] = __float2bfloat16(pf[0][r][1].x);
            pk.hh[5] = __float2bfloat16(pf[0][r][1].y);
            pk.hh[6] = __float2bfloat16(pf[0][r][1].z);
            pk.hh[7] = __float2bfloat16(pf[0][r][1].w);
            const int mi = mi0 + 64 * r;
            *(uint4*)(As0 + ((kc8 * 128 + (mi ^ kc8)) << 4)) = pk.u;
        }
        char* Bs0 = smem + 32768;
        __builtin_amdgcn_global_load_lds(
            (const __attribute__((address_space(1))) void*)bSrc0,
            (__attribute__((address_space(3))) void*)(Bs0 + wave * 1024), 16, 0, 0);
        if (wave < 4)
            __builtin_amdgcn_global_load_lds(
                (const __attribute__((address_space(1))) void*)bSrc1,
                (__attribute__((address_space(3))) void*)(Bs0 + (wave + 8) * 1024), 16, 0, 0);
    }
    {
        const float* src; int rs, c0;
        slab_src(1, x, h_ltc, ctx, src, rs, c0);
        #pragma unroll
        for (int r = 0; r < 2; ++r) {
            const float* p = src + (size_t)(mt * 128 + mi0 + 64 * r) * rs + c0 + kc8 * 8;
            pf[1][r][0] = *(const float4*)p;
            pf[1][r][1] = *(const float4*)(p + 4);
        }
    }
    __syncthreads();   // slab 0 visible in LDS

    for (int ks = 0; ks < 14; ++ks) {
        const int cur = ks & 1, nxt = cur ^ 1;
        char* AsC = smem + cur * 16384;
        char* AsN = smem + nxt * 16384;
        char* BsC = smem + 32768 + cur * 12288;
        char* BsN = smem + 32768 + nxt * 12288;

        // Stage slab ks+1 into the nxt buffers (drains at the barrier AFTER
        // this step's compute — full compute phase of latency hiding).
        if (ks < 13) {
            const int slot = (ks + 1) & 1;   // pf slot holding slab ks+1
            #pragma unroll
            for (int r = 0; r < 2; ++r) {
                union { __hip_bfloat16 hh[8]; uint4 u; } pk;
                pk.hh[0] = __float2bfloat16(pf[slot][r][0].x);
                pk.hh[1] = __float2bfloat16(pf[slot][r][0].y);
                pk.hh[2] = __float2bfloat16(pf[slot][r][0].z);
                pk.hh[3] = __float2bfloat16(pf[slot][r][0].w);
                pk.hh[4] = __float2bfloat16(pf[slot][r][1].x);
                pk.hh[5] = __float2bfloat16(pf[slot][r][1].y);
                pk.hh[6] = __float2bfloat16(pf[slot][r][1].z);
                pk.hh[7] = __float2bfloat16(pf[slot][r][1].w);
                const int mi = mi0 + 64 * r;
                *(uint4*)(AsN + ((kc8 * 128 + (mi ^ kc8)) << 4)) = pk.u;
            }
            const __hip_bfloat16* b0 = bSrc0 + (size_t)(ks + 1) * 6144;
            __builtin_amdgcn_global_load_lds(
                (const __attribute__((address_space(1))) void*)b0,
                (__attribute__((address_space(3))) void*)(BsN + wave * 1024), 16, 0, 0);
            if (wave < 4) {
                const __hip_bfloat16* b1 = bSrc1 + (size_t)(ks + 1) * 6144;
                __builtin_amdgcn_global_load_lds(
                    (const __attribute__((address_space(1))) void*)b1,
                    (__attribute__((address_space(3))) void*)(BsN + (wave + 8) * 1024), 16, 0, 0);
            }
        }
        // Prefetch A slab ks+2 into the pf slot just freed (holds slab ks).
        if (ks < 12) {
            const float* src; int rs, c0;
            slab_src(ks + 2, x, h_ltc, ctx, src, rs, c0);
            const int slot = ks & 1;
            #pragma unroll
            for (int r = 0; r < 2; ++r) {
                const float* p = src + (size_t)(mt * 128 + mi0 + 64 * r) * rs + c0 + kc8 * 8;
                pf[slot][r][0] = *(const float4*)p;
                pf[slot][r][1] = *(const float4*)(p + 4);
            }
        }

        // Compute slab ks from the cur buffers.
        const bool tau_on = (ks >= 2 && ks < 10);  // k in [128,640)
        #pragma unroll
        for (int ko2 = 0; ko2 < 2; ++ko2) {
            const int kcl = ko2 * 4 + q;
            const char* ab = AsC + ((kcl * 128 + wm * 32 + (t ^ kcl)) << 4);
            bf16x8 a0 = *(const bf16x8*)(ab);
            bf16x8 a1 = *(const bf16x8*)(ab + 256);
            const char* bb = BsC + ((kcl * 96 + wj * 48 + t) << 4);
            bf16x8 bg = *(const bf16x8*)(bb);
            bf16x8 bd = *(const bf16x8*)(bb + 256);
            accg[0] = __builtin_amdgcn_mfma_f32_16x16x32_bf16(a0, bg, accg[0], 0, 0, 0);
            accg[1] = __builtin_amdgcn_mfma_f32_16x16x32_bf16(a1, bg, accg[1], 0, 0, 0);
            accd[0] = __builtin_amdgcn_mfma_f32_16x16x32_bf16(a0, bd, accd[0], 0, 0, 0);
            accd[1] = __builtin_amdgcn_mfma_f32_16x16x32_bf16(a1, bd, accd[1], 0, 0, 0);
            if (tau_on) {
                bf16x8 bt = *(const bf16x8*)(bb + 512);
                acct[0] = __builtin_amdgcn_mfma_f32_16x16x32_bf16(a0, bt, acct[0], 0, 0, 0);
                acct[1] = __builtin_amdgcn_mfma_f32_16x16x32_bf16(a1, bt, acct[1], 0, 0, 0);
            }
        }
        __syncthreads();   // drains this step's staging; nxt buffers become cur
    }

    // Epilogue: bias + sigmoid/tanh/softplus + divide, fast-math intrinsics.
    const int row0 = mt * 128 + wm * 32 + q * 4;
    const int j = jt * 32 + wj * 16 + t;
    const float bgj = b_gd[j];
    const float bdj = b_gd[HID + j];
    const float btj = b_tau[j];
    const float dcj = dconst[j];
    #pragma unroll
    for (int i = 0; i < 2; ++i) {
        #pragma unroll
        for (int r = 0; r < 4; ++r) {
            const int row = row0 + i * 16 + r;
            const float gv = accg[i][r] + bgj;
            const float dv = accd[i][r] + bdj;
            const float tp = acct[i][r] + btj;
            const float hv = h_ltc[(size_t)row * HID + j];
            const float sig = __builtin_amdgcn_rcpf(1.0f + __expf(-gv));
            const float th  = 1.0f - 2.0f * __builtin_amdgcn_rcpf(__expf(2.0f * dv) + 1.0f);
            const float tau = fmaxf(tp, 0.0f) + __logf(1.0f + __expf(-fabsf(tp)));
            out[(size_t)row * HID + j] = (sig * th - hv) * __builtin_amdgcn_rcpf(tau + dcj);
        }
    }
}

// ---------------------------------------------------------------------------
extern "C" void kernel_launch(void* const* d_in, const int* in_sizes, int n_in,
                              void* d_out, int out_size, void* d_ws, size_t ws_size,
                              hipStream_t stream) {
    // setup_inputs order: t, h_ltc, x_t, context, W_gd, b_gd, W_tau, b_tau, gleak, cm
    const float* h_ltc = (const float*)d_in[1];
    const float* x_t   = (const float*)d_in[2];
    const float* ctx   = (const float*)d_in[3];
    const float* W_gd  = (const float*)d_in[4];
    const float* b_gd  = (const float*)d_in[5];
    const float* W_tau = (const float*)d_in[6];
    const float* b_tau = (const float*)d_in[7];
    const float* gleak = (const float*)d_in[8];
    const float* cm    = (const float*)d_in[9];

    char* ws = (char*)d_ws;
    __hip_bfloat16* B_stage = (__hip_bfloat16*)ws;      // 16*112*96*8*2 = 2,752,512 B
    float* dconst = (float*)(ws + 2752512);             // 2,048 B

    pack_B<<<672, 256, 0, stream>>>(W_gd, W_tau, gleak, cm, B_stage, dconst);
    ltc_gemm<<<2048, 512, 0, stream>>>(x_t, h_ltc, ctx, B_stage, b_gd, b_tau, dconst,
                                       (float*)d_out);
}

// Round 7
// 171.932 us; speedup vs baseline: 1.1858x; 1.1858x over previous
//
#include <hip/hip_runtime.h>
#include <hip/hip_bf16.h>
#include <math.h>

// Problem constants
#define BROWS 16384
#define IN_DIM 128
#define HID 512
#define ATT 256
#define KTOT 896          // IN_DIM + HID + ATT
#define KC_TOT 112        // KTOT / 8

typedef __bf16 bf16x8 __attribute__((ext_vector_type(8)));
typedef float f32x4 __attribute__((ext_vector_type(4)));

// ---------------------------------------------------------------------------
// Kernel 1: pack augmented weights -> B_stage[jt(8)][kc(112)][nl(192)][8] bf16.
// nl = jg*48 + type*16 + j16 ; jg in [0,4), type 0=gate 1=dyn 2=tau.
// j = jt*64 + jg*16 + j16. tau rows nonzero only for k in [128,640).
// ---------------------------------------------------------------------------
__device__ __forceinline__ float softplus_f(float x) {
    return fmaxf(x, 0.0f) + log1pf(__expf(-fabsf(x)));
}

__global__ void pack_B(const float* __restrict__ W_gd, const float* __restrict__ W_tau,
                       const float* __restrict__ gleak, const float* __restrict__ cm,
                       __hip_bfloat16* __restrict__ B_stage, float* __restrict__ dconst) {
    const int cid = blockIdx.x * 256 + threadIdx.x;   // 672*256 = 172032 = 8*112*192
    if (cid < HID) {
        dconst[cid] = softplus_f(cm[cid]) + softplus_f(gleak[cid]) + 1e-6f;
    }
    const int nl = cid % 192;
    const int kc = (cid / 192) % KC_TOT;
    const int jt = cid / (192 * KC_TOT);
    const int jg = nl / 48, type = (nl % 48) / 16, j16 = nl % 16;
    const int j = jt * 64 + jg * 16 + j16;
    const int k0 = kc * 8;

    float v[8];
    if (type == 0) {
        const float* s = W_gd + (size_t)j * KTOT + k0;
        #pragma unroll
        for (int i = 0; i < 8; ++i) v[i] = s[i];
    } else if (type == 1) {
        const float* s = W_gd + (size_t)(HID + j) * KTOT + k0;
        #pragma unroll
        for (int i = 0; i < 8; ++i) v[i] = s[i];
    } else {
        if (k0 >= IN_DIM && k0 < IN_DIM + HID) {
            const float* s = W_tau + (size_t)j * HID + (k0 - IN_DIM);
            #pragma unroll
            for (int i = 0; i < 8; ++i) v[i] = s[i];
        } else {
            #pragma unroll
            for (int i = 0; i < 8; ++i) v[i] = 0.0f;
        }
    }
    union { __hip_bfloat16 hh[8]; uint4 u; } p;
    #pragma unroll
    for (int i = 0; i < 8; ++i) p.hh[i] = __float2bfloat16(v[i]);
    *(uint4*)(B_stage + (size_t)cid * 8) = p.u;
}

// ---------------------------------------------------------------------------
// Kernel 2: fused convert+GEMM+epilogue. B via REGISTERS (no LDS, no barrier
// coupling), A via double-buffered LDS with ONE barrier per step.
//   - B_stage is 2.75MB -> L2-resident; each wave loads its 6 fragments/step
//     as coalesced 256B segments straight to VGPRs. The s_waitcnt vmcnt for
//     them is per-wave (waves slip independently) — removes the block-wide
//     vmcnt(0) barrier drain that bound R2/R4/R5 (m97 structural stall).
//   - A: 3-stage pipeline: global->pf regs (step ks-1), convert+ds_write
//     As[nxt] (step ks), ds_read+MFMA (step ks+1). Barrier drains lgkm only.
// Block: 512 thr (8 waves), tile 128(M) x 64(j) x {gate,dyn,tau}, BK=64.
// Waves: wm = wave>>2 (64-row half), wj = wave&3 (16-j group). acc = 48 regs.
// Grid: 1024 blocks (mt = bx & 127 -> co-XCD A-tile siblings, keeps FETCH
// ~110MB — R6's jt=16 split doubled logical A traffic and blew L3: 240MB).
// LDS: 2 x 16KB = 32KB. Regs ~118 unified (48 acc + 24 Bv + 16 pf + misc)
// under the (512,4) cap of 128 — R3 lesson: never force a spill.
// ---------------------------------------------------------------------------
__device__ __forceinline__ void slab_src(int ks, const float* x, const float* h,
                                         const float* c, const float*& src,
                                         int& rs, int& c0) {
    if (ks < 2)       { src = x; rs = IN_DIM; c0 = ks * 64; }
    else if (ks < 10) { src = h; rs = HID;    c0 = (ks - 2) * 64; }
    else              { src = c; rs = ATT;    c0 = (ks - 10) * 64; }
}

__global__ __launch_bounds__(512, 4) void ltc_gemm(
    const float* __restrict__ x, const float* __restrict__ h_ltc,
    const float* __restrict__ ctx, const __hip_bfloat16* __restrict__ B_stage,
    const float* __restrict__ b_gd, const float* __restrict__ b_tau,
    const float* __restrict__ dconst, float* __restrict__ out) {

    __shared__ __attribute__((aligned(16))) char smem[2 * 16384];

    const int bx = blockIdx.x;
    const int mt = bx & 127;    // A-tile id; bx % 8 == mt % 8 -> co-XCD siblings
    const int jt = bx >> 7;     // 0..7
    const int tid = threadIdx.x;
    const int wave = tid >> 6, lane = tid & 63;
    const int wm = wave >> 2;   // 0..1  M half (64 rows)
    const int wj = wave & 3;    // 0..3  16-j group
    const int q = lane >> 4, t = lane & 15;

    // A staging role: thread stages chunks (kc8, mi0) and (kc8, mi0+64)
    const int kc8 = tid & 7;    // k-chunk in slab
    const int mi0 = tid >> 3;   // 0..63

    f32x4 accg[4], accd[4], acct[4];
    #pragma unroll
    for (int i = 0; i < 4; ++i) {
        accg[i] = (f32x4)0.0f; accd[i] = (f32x4)0.0f; acct[i] = (f32x4)0.0f;
    }

    // B register-load base: elem addr = ((jt*112 + kcg)*192 + wj*48 + ty*16 + t)*8
    const __hip_bfloat16* bBase = B_stage + (size_t)jt * (KC_TOT * 1536)
                                + (size_t)(wj * 48 + t) * 8;

    // --- Prologue ---
    float4 pf[2][2];   // [r][half] : A slab prefetch, 16 VGPRs
    {
        const float* src; int rs, c0;
        slab_src(0, x, h_ltc, ctx, src, rs, c0);
        #pragma unroll
        for (int r = 0; r < 2; ++r) {
            const float* p = src + (size_t)(mt * 128 + mi0 + 64 * r) * rs + c0 + kc8 * 8;
            pf[r][0] = *(const float4*)p;
            pf[r][1] = *(const float4*)(p + 4);
        }
    }
    {
        char* As0 = smem;
        #pragma unroll
        for (int r = 0; r < 2; ++r) {
            union { __hip_bfloat16 hh[8]; uint4 u; } pk;
            pk.hh[0] = __float2bfloat16(pf[r][0].x);
            pk.hh[1] = __float2bfloat16(pf[r][0].y);
            pk.hh[2] = __float2bfloat16(pf[r][0].z);
            pk.hh[3] = __float2bfloat16(pf[r][0].w);
            pk.hh[4] = __float2bfloat16(pf[r][1].x);
            pk.hh[5] = __float2bfloat16(pf[r][1].y);
            pk.hh[6] = __float2bfloat16(pf[r][1].z);
            pk.hh[7] = __float2bfloat16(pf[r][1].w);
            const int mi = mi0 + 64 * r;
            *(uint4*)(As0 + ((kc8 * 128 + (mi ^ kc8)) << 4)) = pk.u;
        }
    }
    {
        const float* src; int rs, c0;
        slab_src(1, x, h_ltc, ctx, src, rs, c0);
        #pragma unroll
        for (int r = 0; r < 2; ++r) {
            const float* p = src + (size_t)(mt * 128 + mi0 + 64 * r) * rs + c0 + kc8 * 8;
            pf[r][0] = *(const float4*)p;
            pf[r][1] = *(const float4*)(p + 4);
        }
    }
    __syncthreads();   // slab 0 visible in LDS (lgkm drain only)

    #pragma unroll
    for (int ks = 0; ks < 14; ++ks) {
        char* AsC = smem + (ks & 1) * 16384;
        char* AsN = smem + ((ks & 1) ^ 1) * 16384;
        const bool tau_on = (ks >= 2 && ks < 10);  // k in [128,640)

        // Issue this slab's B fragment loads early (regs; per-wave waitcnt).
        bf16x8 Bv[2][3];
        #pragma unroll
        for (int ko2 = 0; ko2 < 2; ++ko2) {
            const int kcl = ko2 * 4 + q;
            const __hip_bfloat16* bp = bBase + (size_t)(ks * 8 + kcl) * 1536;
            Bv[ko2][0] = *(const bf16x8*)(bp);
            Bv[ko2][1] = *(const bf16x8*)(bp + 128);
            if (tau_on) Bv[ko2][2] = *(const bf16x8*)(bp + 256);
        }

        // Stage A slab ks+1 into AsN (pf has had a full step in flight).
        if (ks < 13) {
            #pragma unroll
            for (int r = 0; r < 2; ++r) {
                union { __hip_bfloat16 hh[8]; uint4 u; } pk;
                pk.hh[0] = __float2bfloat16(pf[r][0].x);
                pk.hh[1] = __float2bfloat16(pf[r][0].y);
                pk.hh[2] = __float2bfloat16(pf[r][0].z);
                pk.hh[3] = __float2bfloat16(pf[r][0].w);
                pk.hh[4] = __float2bfloat16(pf[r][1].x);
                pk.hh[5] = __float2bfloat16(pf[r][1].y);
                pk.hh[6] = __float2bfloat16(pf[r][1].z);
                pk.hh[7] = __float2bfloat16(pf[r][1].w);
                const int mi = mi0 + 64 * r;
                *(uint4*)(AsN + ((kc8 * 128 + (mi ^ kc8)) << 4)) = pk.u;
            }
        }
        // Prefetch A slab ks+2 (drains at its use, two steps out).
        if (ks < 12) {
            const float* src; int rs, c0;
            slab_src(ks + 2, x, h_ltc, ctx, src, rs, c0);
            #pragma unroll
            for (int r = 0; r < 2; ++r) {
                const float* p = src + (size_t)(mt * 128 + mi0 + 64 * r) * rs + c0 + kc8 * 8;
                pf[r][0] = *(const float4*)p;
                pf[r][1] = *(const float4*)(p + 4);
            }
        }

        // Compute slab ks: A from LDS, B from regs.
        #pragma unroll
        for (int ko2 = 0; ko2 < 2; ++ko2) {
            const int kcl = ko2 * 4 + q;
            const char* ab = AsC + ((kcl * 128 + ((wm * 64 + t) ^ kcl)) << 4);
            bf16x8 a0 = *(const bf16x8*)(ab);
            bf16x8 a1 = *(const bf16x8*)(ab + 256);
            bf16x8 a2 = *(const bf16x8*)(ab + 512);
            bf16x8 a3 = *(const bf16x8*)(ab + 768);
            accg[0] = __builtin_amdgcn_mfma_f32_16x16x32_bf16(a0, Bv[ko2][0], accg[0], 0, 0, 0);
            accg[1] = __builtin_amdgcn_mfma_f32_16x16x32_bf16(a1, Bv[ko2][0], accg[1], 0, 0, 0);
            accg[2] = __builtin_amdgcn_mfma_f32_16x16x32_bf16(a2, Bv[ko2][0], accg[2], 0, 0, 0);
            accg[3] = __builtin_amdgcn_mfma_f32_16x16x32_bf16(a3, Bv[ko2][0], accg[3], 0, 0, 0);
            accd[0] = __builtin_amdgcn_mfma_f32_16x16x32_bf16(a0, Bv[ko2][1], accd[0], 0, 0, 0);
            accd[1] = __builtin_amdgcn_mfma_f32_16x16x32_bf16(a1, Bv[ko2][1], accd[1], 0, 0, 0);
            accd[2] = __builtin_amdgcn_mfma_f32_16x16x32_bf16(a2, Bv[ko2][1], accd[2], 0, 0, 0);
            accd[3] = __builtin_amdgcn_mfma_f32_16x16x32_bf16(a3, Bv[ko2][1], accd[3], 0, 0, 0);
            if (tau_on) {
                acct[0] = __builtin_amdgcn_mfma_f32_16x16x32_bf16(a0, Bv[ko2][2], acct[0], 0, 0, 0);
                acct[1] = __builtin_amdgcn_mfma_f32_16x16x32_bf16(a1, Bv[ko2][2], acct[1], 0, 0, 0);
                acct[2] = __builtin_amdgcn_mfma_f32_16x16x32_bf16(a2, Bv[ko2][2], acct[2], 0, 0, 0);
                acct[3] = __builtin_amdgcn_mfma_f32_16x16x32_bf16(a3, Bv[ko2][2], acct[3], 0, 0, 0);
            }
        }
        __syncthreads();   // lgkm drain only (ds_write AsN); AsN becomes AsC
    }

    // Epilogue: bias + sigmoid/tanh/softplus + divide, fast-math intrinsics.
    const int row0 = mt * 128 + wm * 64 + q * 4;
    const int j = jt * 64 + wj * 16 + t;
    const float bgj = b_gd[j];
    const float bdj = b_gd[HID + j];
    const float btj = b_tau[j];
    const float dcj = dconst[j];
    #pragma unroll
    for (int i = 0; i < 4; ++i) {
        #pragma unroll
        for (int r = 0; r < 4; ++r) {
            const int row = row0 + i * 16 + r;
            const float gv = accg[i][r] + bgj;
            const float dv = accd[i][r] + bdj;
            const float tp = acct[i][r] + btj;
            const float hv = h_ltc[(size_t)row * HID + j];
            const float sig = __builtin_amdgcn_rcpf(1.0f + __expf(-gv));
            const float th  = 1.0f - 2.0f * __builtin_amdgcn_rcpf(__expf(2.0f * dv) + 1.0f);
            const float tau = fmaxf(tp, 0.0f) + __logf(1.0f + __expf(-fabsf(tp)));
            out[(size_t)row * HID + j] = (sig * th - hv) * __builtin_amdgcn_rcpf(tau + dcj);
        }
    }
}

// ---------------------------------------------------------------------------
extern "C" void kernel_launch(void* const* d_in, const int* in_sizes, int n_in,
                              void* d_out, int out_size, void* d_ws, size_t ws_size,
                              hipStream_t stream) {
    // setup_inputs order: t, h_ltc, x_t, context, W_gd, b_gd, W_tau, b_tau, gleak, cm
    const float* h_ltc = (const float*)d_in[1];
    const float* x_t   = (const float*)d_in[2];
    const float* ctx   = (const float*)d_in[3];
    const float* W_gd  = (const float*)d_in[4];
    const float* b_gd  = (const float*)d_in[5];
    const float* W_tau = (const float*)d_in[6];
    const float* b_tau = (const float*)d_in[7];
    const float* gleak = (const float*)d_in[8];
    const float* cm    = (const float*)d_in[9];

    char* ws = (char*)d_ws;
    __hip_bfloat16* B_stage = (__hip_bfloat16*)ws;      // 8*112*192*8*2 = 2,752,512 B
    float* dconst = (float*)(ws + 2752512);             // 2,048 B

    pack_B<<<672, 256, 0, stream>>>(W_gd, W_tau, gleak, cm, B_stage, dconst);
    ltc_gemm<<<1024, 512, 0, stream>>>(x_t, h_ltc, ctx, B_stage, b_gd, b_tau, dconst,
                                       (float*)d_out);
}

// Round 8
// 165.659 us; speedup vs baseline: 1.2307x; 1.0379x over previous
//
#include <hip/hip_runtime.h>
#include <hip/hip_bf16.h>
#include <math.h>

// Problem constants
#define BROWS 16384
#define IN_DIM 128
#define HID 512
#define ATT 256
#define KTOT 896          // IN_DIM + HID + ATT
#define KC_TOT 112        // KTOT / 8

typedef __bf16 bf16x8 __attribute__((ext_vector_type(8)));
typedef float f32x4 __attribute__((ext_vector_type(4)));

// ---------------------------------------------------------------------------
// Kernel 1: pack augmented weights -> B_stage[jt(8)][kc(112)][nl(192)][8] bf16.
// nl = jg*48 + type*16 + j16 ; jg in [0,4), type 0=gate 1=dyn 2=tau.
// j = jt*64 + jg*16 + j16. tau rows ZERO outside k in [128,640).
// ---------------------------------------------------------------------------
__device__ __forceinline__ float softplus_f(float x) {
    return fmaxf(x, 0.0f) + log1pf(__expf(-fabsf(x)));
}

__global__ void pack_B(const float* __restrict__ W_gd, const float* __restrict__ W_tau,
                       const float* __restrict__ gleak, const float* __restrict__ cm,
                       __hip_bfloat16* __restrict__ B_stage, float* __restrict__ dconst) {
    const int cid = blockIdx.x * 256 + threadIdx.x;   // 672*256 = 172032 = 8*112*192
    if (cid < HID) {
        dconst[cid] = softplus_f(cm[cid]) + softplus_f(gleak[cid]) + 1e-6f;
    }
    const int nl = cid % 192;
    const int kc = (cid / 192) % KC_TOT;
    const int jt = cid / (192 * KC_TOT);
    const int jg = nl / 48, type = (nl % 48) / 16, j16 = nl % 16;
    const int j = jt * 64 + jg * 16 + j16;
    const int k0 = kc * 8;

    float v[8];
    if (type == 0) {
        const float* s = W_gd + (size_t)j * KTOT + k0;
        #pragma unroll
        for (int i = 0; i < 8; ++i) v[i] = s[i];
    } else if (type == 1) {
        const float* s = W_gd + (size_t)(HID + j) * KTOT + k0;
        #pragma unroll
        for (int i = 0; i < 8; ++i) v[i] = s[i];
    } else {
        if (k0 >= IN_DIM && k0 < IN_DIM + HID) {
            const float* s = W_tau + (size_t)j * HID + (k0 - IN_DIM);
            #pragma unroll
            for (int i = 0; i < 8; ++i) v[i] = s[i];
        } else {
            #pragma unroll
            for (int i = 0; i < 8; ++i) v[i] = 0.0f;
        }
    }
    union { __hip_bfloat16 hh[8]; uint4 u; } p;
    #pragma unroll
    for (int i = 0; i < 8; ++i) p.hh[i] = __float2bfloat16(v[i]);
    *(uint4*)(B_stage + (size_t)cid * 8) = p.u;
}

// ---------------------------------------------------------------------------
// Kernel 2: BARRIER-FREE K-loop GEMM.
// Each block owns 32 rows and ALL 512 j. Full-K A tile (32 x 896, bf16) is
// staged to LDS ONCE (one __syncthreads), then the j-loop x K-loop runs with
// ZERO barriers: A-frags via conflict-free XOR-swizzled ds_read_b128, B-frags
// register-loaded from the 2.75MB L2-resident B_stage with an explicit
// one-step register double-buffer. No barrier exists to force-drain the
// loads (the m97 vmcnt(0)-before-s_barrier stall that pinned R2-R7 at
// 57-78us). A is HBM-read exactly once (59MB total, no jt redundancy).
// Block: 512 thr (8 waves). Per iter (4 iters): wave computes 32 rows x 16 j.
// LDS: 112 kc x 32 mi x 16B = 56KB static (<=64KB safe) -> 2 blocks/CU.
// Grid: 512 blocks = exactly 2/CU. Regs ~95 (acc 24 + abuf 16 + bbuf 24 +
// misc) under the (512,4) cap of 128 — R3/R7 lesson: no spill.
// ---------------------------------------------------------------------------
__global__ __launch_bounds__(512, 4) void ltc_gemm(
    const float* __restrict__ x, const float* __restrict__ h_ltc,
    const float* __restrict__ ctx, const __hip_bfloat16* __restrict__ B_stage,
    const float* __restrict__ b_gd, const float* __restrict__ b_tau,
    const float* __restrict__ dconst, float* __restrict__ out) {

    __shared__ __attribute__((aligned(16))) char As[57344];  // [kc 112][mi 32] 16B

    const int mt = blockIdx.x;          // 0..511 : rows mt*32 .. mt*32+31
    const int tid = threadIdx.x;
    const int wave = tid >> 6, lane = tid & 63;
    const int q = lane >> 4, t = lane & 15;

    // ---- Stage A (fp32 -> bf16) once. thread (mi, kcg) stages 7 chunks. ----
    const int mi = tid >> 4;            // 0..31
    const int kcg = tid & 15;           // 0..15
    #pragma unroll
    for (int s = 0; s < 7; ++s) {
        const int kc = kcg + 16 * s;
        const float* src; int rs, col;
        if (s == 0)      { src = x;     rs = IN_DIM; col = kcg * 8; }
        else if (s < 5)  { src = h_ltc; rs = HID;    col = kcg * 8 + (s - 1) * 128; }
        else             { src = ctx;   rs = ATT;    col = kcg * 8 + (s - 5) * 128; }
        const float* p = src + (size_t)(mt * 32 + mi) * rs + col;
        float4 v0 = *(const float4*)p;
        float4 v1 = *(const float4*)(p + 4);
        union { __hip_bfloat16 hh[8]; uint4 u; } pk;
        pk.hh[0] = __float2bfloat16(v0.x); pk.hh[1] = __float2bfloat16(v0.y);
        pk.hh[2] = __float2bfloat16(v0.z); pk.hh[3] = __float2bfloat16(v0.w);
        pk.hh[4] = __float2bfloat16(v1.x); pk.hh[5] = __float2bfloat16(v1.y);
        pk.hh[6] = __float2bfloat16(v1.z); pk.hh[7] = __float2bfloat16(v1.w);
        *(uint4*)(As + ((kc * 32 + (mi ^ (kc & 31))) << 4)) = pk.u;
    }
    __syncthreads();   // the ONLY barrier in this kernel

    // ---- j-loop: 4 iters x (8 waves x 16 j) covers all 512 j ----
    for (int it = 0; it < 4; ++it) {
        const int jglob = it * 128 + wave * 16;       // this wave's j base
        const int jt = jglob >> 6;                    // 0..7
        const int jg = (jglob >> 4) & 3;              // 0..3
        const __hip_bfloat16* bBase = B_stage
            + ((size_t)jt * (KC_TOT * 192) + jg * 48 + t) * 8;

        f32x4 acc[2][3];
        #pragma unroll
        for (int f = 0; f < 2; ++f)
            #pragma unroll
            for (int ty = 0; ty < 3; ++ty) acc[f][ty] = (f32x4)0.0f;

        // register double-buffers for the software pipeline (no barriers!)
        bf16x8 ab[2][2]; bf16x8 bb[2][3];

        // prefetch step 0
        {
            const int kc = q;   // kst=0
            ab[0][0] = *(const bf16x8*)(As + ((kc * 32 + (t ^ kc)) << 4));
            ab[0][1] = *(const bf16x8*)(As + ((kc * 32 + ((16 + t) ^ kc)) << 4));
            const __hip_bfloat16* bp = bBase + (size_t)kc * 1536;
            bb[0][0] = *(const bf16x8*)(bp);
            bb[0][1] = *(const bf16x8*)(bp + 128);
        }

        #pragma unroll 4
        for (int kst = 0; kst < 28; ++kst) {
            const int cb = kst & 1, nb = cb ^ 1;
            const bool tau_cur = (kst >= 4 && kst < 20);   // k in [128,640)
            // issue next step's loads first — they retire while we MFMA
            if (kst < 27) {
                const int kc = (kst + 1) * 4 + q;
                const int sw = kc & 31;
                ab[nb][0] = *(const bf16x8*)(As + ((kc * 32 + (t ^ sw)) << 4));
                ab[nb][1] = *(const bf16x8*)(As + ((kc * 32 + ((16 + t) ^ sw)) << 4));
                const __hip_bfloat16* bp = bBase + (size_t)kc * 1536;
                bb[nb][0] = *(const bf16x8*)(bp);
                bb[nb][1] = *(const bf16x8*)(bp + 128);
                if (kst + 1 >= 4 && kst + 1 < 20)
                    bb[nb][2] = *(const bf16x8*)(bp + 256);
            }
            acc[0][0] = __builtin_amdgcn_mfma_f32_16x16x32_bf16(ab[cb][0], bb[cb][0], acc[0][0], 0, 0, 0);
            acc[1][0] = __builtin_amdgcn_mfma_f32_16x16x32_bf16(ab[cb][1], bb[cb][0], acc[1][0], 0, 0, 0);
            acc[0][1] = __builtin_amdgcn_mfma_f32_16x16x32_bf16(ab[cb][0], bb[cb][1], acc[0][1], 0, 0, 0);
            acc[1][1] = __builtin_amdgcn_mfma_f32_16x16x32_bf16(ab[cb][1], bb[cb][1], acc[1][1], 0, 0, 0);
            if (tau_cur) {
                acc[0][2] = __builtin_amdgcn_mfma_f32_16x16x32_bf16(ab[cb][0], bb[cb][2], acc[0][2], 0, 0, 0);
                acc[1][2] = __builtin_amdgcn_mfma_f32_16x16x32_bf16(ab[cb][1], bb[cb][2], acc[1][2], 0, 0, 0);
            }
        }

        // ---- epilogue for this wave's 32 rows x 16 j ----
        const int j = jglob + t;
        const float bgj = b_gd[j];
        const float bdj = b_gd[HID + j];
        const float btj = b_tau[j];
        const float dcj = dconst[j];
        #pragma unroll
        for (int f = 0; f < 2; ++f) {
            #pragma unroll
            for (int r = 0; r < 4; ++r) {
                const int row = mt * 32 + f * 16 + q * 4 + r;
                const float gv = acc[f][0][r] + bgj;
                const float dv = acc[f][1][r] + bdj;
                const float tp = acc[f][2][r] + btj;
                const float hv = h_ltc[(size_t)row * HID + j];
                const float sig = __builtin_amdgcn_rcpf(1.0f + __expf(-gv));
                const float th  = 1.0f - 2.0f * __builtin_amdgcn_rcpf(__expf(2.0f * dv) + 1.0f);
                const float tau = fmaxf(tp, 0.0f) + __logf(1.0f + __expf(-fabsf(tp)));
                out[(size_t)row * HID + j] = (sig * th - hv) * __builtin_amdgcn_rcpf(tau + dcj);
            }
        }
    }
}

// ---------------------------------------------------------------------------
extern "C" void kernel_launch(void* const* d_in, const int* in_sizes, int n_in,
                              void* d_out, int out_size, void* d_ws, size_t ws_size,
                              hipStream_t stream) {
    // setup_inputs order: t, h_ltc, x_t, context, W_gd, b_gd, W_tau, b_tau, gleak, cm
    const float* h_ltc = (const float*)d_in[1];
    const float* x_t   = (const float*)d_in[2];
    const float* ctx   = (const float*)d_in[3];
    const float* W_gd  = (const float*)d_in[4];
    const float* b_gd  = (const float*)d_in[5];
    const float* W_tau = (const float*)d_in[6];
    const float* b_tau = (const float*)d_in[7];
    const float* gleak = (const float*)d_in[8];
    const float* cm    = (const float*)d_in[9];

    char* ws = (char*)d_ws;
    __hip_bfloat16* B_stage = (__hip_bfloat16*)ws;      // 8*112*192*8*2 = 2,752,512 B
    float* dconst = (float*)(ws + 2752512);             // 2,048 B

    pack_B<<<672, 256, 0, stream>>>(W_gd, W_tau, gleak, cm, B_stage, dconst);
    ltc_gemm<<<512, 512, 0, stream>>>(x_t, h_ltc, ctx, B_stage, b_gd, b_tau, dconst,
                                      (float*)d_out);
}